// Round 1
// baseline (670.659 us; speedup 1.0000x reference)
//
#include <hip/hip_runtime.h>

#define N_NODES 100000
#define N_EDGES 1600000
#define HID 64

__device__ __forceinline__ float bcastf(float v, int lane) {
    return __int_as_float(__builtin_amdgcn_readlane(__float_as_int(v), lane));
}

// h = relu(x @ preW.T + preb), x: [N,3], preW: [64,3]
__global__ void pre_kernel(const float* __restrict__ x, const float* __restrict__ W,
                           const float* __restrict__ b, float* __restrict__ h) {
    int tid = blockIdx.x * blockDim.x + threadIdx.x;
    if (tid >= N_NODES * HID) return;
    int i = tid >> 6, j = tid & 63;
    float acc = b[j];
    acc = fmaf(x[i * 3 + 0], W[j * 3 + 0], acc);
    acc = fmaf(x[i * 3 + 1], W[j * 3 + 1], acc);
    acc = fmaf(x[i * 3 + 2], W[j * 3 + 2], acc);
    h[tid] = fmaxf(acc, 0.f);
}

__global__ void hist_kernel(const int* __restrict__ dst, int* __restrict__ deg) {
    int e = blockIdx.x * blockDim.x + threadIdx.x;
    if (e < N_EDGES) atomicAdd(&deg[dst[e]], 1);
}

// per-block inclusive scan of deg -> linc, block total -> bsum
__global__ void scan_a(const int* __restrict__ deg, int* __restrict__ linc,
                       int* __restrict__ bsum) {
    __shared__ int s[256];
    int t = threadIdx.x, i = blockIdx.x * 256 + t;
    int v = (i < N_NODES) ? deg[i] : 0;
    s[t] = v;
    __syncthreads();
    for (int off = 1; off < 256; off <<= 1) {
        int add = (t >= off) ? s[t - off] : 0;
        __syncthreads();
        s[t] += add;
        __syncthreads();
    }
    if (i < N_NODES) linc[i] = s[t];
    if (t == 255) bsum[blockIdx.x] = s[255];
}

// scan of block sums -> exclusive boff; also writes rowp[N] = total edges
__global__ void scan_b(const int* __restrict__ bsum, int* __restrict__ boff, int nb,
                       int* __restrict__ rowp) {
    __shared__ int s[512];
    int t = threadIdx.x;
    int v = (t < nb) ? bsum[t] : 0;
    s[t] = v;
    __syncthreads();
    for (int off = 1; off < 512; off <<= 1) {
        int add = (t >= off) ? s[t - off] : 0;
        __syncthreads();
        s[t] += add;
        __syncthreads();
    }
    if (t < nb) boff[t] = s[t] - v;
    if (t == nb - 1) rowp[N_NODES] = s[t];
}

__global__ void scan_c(const int* __restrict__ deg, const int* __restrict__ linc,
                       const int* __restrict__ boff, int* __restrict__ rowp,
                       int* __restrict__ cursor) {
    int i = blockIdx.x * blockDim.x + threadIdx.x;
    if (i >= N_NODES) return;
    int excl = linc[i] - deg[i] + boff[i >> 8];
    rowp[i] = excl;
    cursor[i] = excl;
}

__global__ void scatter_kernel(const int* __restrict__ src, const int* __restrict__ dst,
                               int* __restrict__ cursor, int* __restrict__ ssrc) {
    int e = blockIdx.x * blockDim.x + threadIdx.x;
    if (e >= N_EDGES) return;
    int d = dst[e];
    int pos = atomicAdd(&cursor[d], 1);
    ssrc[pos] = src[e];
}

// m = h @ relW.T ; aout = h @ rootW.T + relb.  Wave-per-node, W in VGPRs,
// h-row broadcast via v_readlane (SGPR operand into v_fmac).
__global__ void gemm2_kernel(const float* __restrict__ h, const float* __restrict__ relW,
                             const float* __restrict__ relb, const float* __restrict__ rootW,
                             float* __restrict__ m, float* __restrict__ aout) {
    int lane = threadIdx.x & 63;
    int wave = (blockIdx.x * blockDim.x + threadIdx.x) >> 6;
    int nwaves = (gridDim.x * blockDim.x) >> 6;
    float wr[64], wo[64];
#pragma unroll
    for (int k = 0; k < 64; k++) {
        wr[k] = relW[lane * 64 + k];
        wo[k] = rootW[lane * 64 + k];
    }
    float bb = relb[lane];
    for (int i = wave; i < N_NODES; i += nwaves) {
        float hv = h[i * 64 + lane];
        float am = 0.f, aa = 0.f;
#pragma unroll
        for (int k = 0; k < 64; k++) {
            float hk = bcastf(hv, k);
            am = fmaf(hk, wr[k], am);
            aa = fmaf(hk, wo[k], aa);
        }
        m[i * 64 + lane] = am;
        aout[i * 64 + lane] = aa + bb;
    }
}

// a[i] = relu(a[i] + sum_{e in CSR row i} m[ssrc[e]]) ; FINAL fuses post layer.
template <int FINAL>
__global__ void gather_kernel(const float* __restrict__ m, float* __restrict__ a,
                              const int* __restrict__ rowp, const int* __restrict__ ssrc,
                              const float* __restrict__ postW, const float* __restrict__ postb,
                              float* __restrict__ out) {
    int lane = threadIdx.x & 63;
    int node = (blockIdx.x * blockDim.x + threadIdx.x) >> 6;
    if (node >= N_NODES) return;
    int r0 = rowp[node], r1 = rowp[node + 1];
    float acc = a[node * 64 + lane];
    for (int base = r0; base < r1; base += 64) {
        int cnt = r1 - base;
        if (cnt > 64) cnt = 64;
        int sv = (base + lane < r1) ? ssrc[base + lane] : 0;
        int e = 0;
        for (; e + 4 <= cnt; e += 4) {
            int s0 = __builtin_amdgcn_readlane(sv, e);
            int s1 = __builtin_amdgcn_readlane(sv, e + 1);
            int s2 = __builtin_amdgcn_readlane(sv, e + 2);
            int s3 = __builtin_amdgcn_readlane(sv, e + 3);
            float v0 = m[(long)s0 * 64 + lane];
            float v1 = m[(long)s1 * 64 + lane];
            float v2 = m[(long)s2 * 64 + lane];
            float v3 = m[(long)s3 * 64 + lane];
            acc += v0; acc += v1; acc += v2; acc += v3;
        }
        for (; e < cnt; ++e) {
            int s0 = __builtin_amdgcn_readlane(sv, e);
            acc += m[(long)s0 * 64 + lane];
        }
    }
    acc = fmaxf(acc, 0.f);
    if (FINAL) {
        float p0 = acc * postW[lane];
        float p1 = acc * postW[64 + lane];
#pragma unroll
        for (int off = 32; off >= 1; off >>= 1) {
            p0 += __shfl_xor(p0, off, 64);
            p1 += __shfl_xor(p1, off, 64);
        }
        if (lane == 0) {
            out[node * 2 + 0] = fmaxf(p0 + postb[0], 0.f);
            out[node * 2 + 1] = fmaxf(p1 + postb[1], 0.f);
        }
    } else {
        a[node * 64 + lane] = acc;
    }
}

extern "C" void kernel_launch(void* const* d_in, const int* in_sizes, int n_in,
                              void* d_out, int out_size, void* d_ws, size_t ws_size,
                              hipStream_t stream) {
    const float* x = (const float*)d_in[0];
    const int* esrc = (const int*)d_in[1];
    const int* edst = esrc + N_EDGES;
    const float* preW = (const float*)d_in[2];
    const float* preb = (const float*)d_in[3];
    const float* postW = (const float*)d_in[4];
    const float* postb = (const float*)d_in[5];
    const float* relW[3] = {(const float*)d_in[6], (const float*)d_in[9], (const float*)d_in[12]};
    const float* relb[3] = {(const float*)d_in[7], (const float*)d_in[10], (const float*)d_in[13]};
    const float* rootW[3] = {(const float*)d_in[8], (const float*)d_in[11], (const float*)d_in[14]};
    float* out = (float*)d_out;

    const size_t NF = (size_t)N_NODES * HID;
    char* p = (char*)d_ws;
    float* hA = (float*)p; p += NF * 4;
    float* hB = (float*)p; p += NF * 4;
    float* mB = (float*)p; p += NF * 4;
    int* deg = (int*)p; p += (size_t)N_NODES * 4;
    int* rowp = (int*)p; p += (size_t)(N_NODES + 1) * 4;
    p = (char*)(((size_t)p + 255) & ~(size_t)255);
    int* cursor = (int*)p; p += (size_t)N_NODES * 4;
    int* ssrc = (int*)p; p += (size_t)N_EDGES * 4;
    int* bsum = (int*)p; p += 512 * 4;
    int* boff = (int*)p; p += 512 * 4;

    const int NB_SCAN = (N_NODES + 255) / 256;  // 391

    // --- build CSR (by dst) ---
    hipMemsetAsync(deg, 0, (size_t)N_NODES * 4, stream);
    hist_kernel<<<(N_EDGES + 255) / 256, 256, 0, stream>>>(edst, deg);
    scan_a<<<NB_SCAN, 256, 0, stream>>>(deg, cursor /*linc temp*/, bsum);
    scan_b<<<1, 512, 0, stream>>>(bsum, boff, NB_SCAN, rowp);
    scan_c<<<NB_SCAN, 256, 0, stream>>>(deg, cursor, boff, rowp, cursor);
    scatter_kernel<<<(N_EDGES + 255) / 256, 256, 0, stream>>>(esrc, edst, cursor, ssrc);

    // --- pre layer ---
    pre_kernel<<<(N_NODES * HID + 255) / 256, 256, 0, stream>>>(x, preW, preb, hA);

    const int GEMM_BLOCKS = 768;
    const int GATHER_BLOCKS = (N_NODES + 3) / 4;  // 4 waves/block, wave-per-node

    // layer 0: hA -> hB
    gemm2_kernel<<<GEMM_BLOCKS, 256, 0, stream>>>(hA, relW[0], relb[0], rootW[0], mB, hB);
    gather_kernel<0><<<GATHER_BLOCKS, 256, 0, stream>>>(mB, hB, rowp, ssrc, nullptr, nullptr, nullptr);
    // layer 1: hB -> hA
    gemm2_kernel<<<GEMM_BLOCKS, 256, 0, stream>>>(hB, relW[1], relb[1], rootW[1], mB, hA);
    gather_kernel<0><<<GATHER_BLOCKS, 256, 0, stream>>>(mB, hA, rowp, ssrc, nullptr, nullptr, nullptr);
    // layer 2: hA -> hB, fused post layer -> out
    gemm2_kernel<<<GEMM_BLOCKS, 256, 0, stream>>>(hA, relW[2], relb[2], rootW[2], mB, hB);
    gather_kernel<1><<<GATHER_BLOCKS, 256, 0, stream>>>(mB, hB, rowp, ssrc, postW, postb, out);
}